// Round 6
// baseline (87.125 us; speedup 1.0000x reference)
//
#include <hip/hip_runtime.h>

#define INFV 1000000000.0f
#define EPSV 1e-6f
#define GP   35          // padded grid pitch (odd -> conflict-free row AND col b32 access)
#define GSZ  1192        // 34*35 = 1190, padded to float4 multiple
#define WP   33          // weight staging pitch (odd)
#define WSZ  1056        // 32*33

// lane i-1 -> lane i (row above). Lane 0 gets 0 (bound_ctrl) -> masked by edge select.
__device__ __forceinline__ float dpp_shr1(float x) {
    int r = __builtin_amdgcn_update_dpp(0, __builtin_bit_cast(int, x),
                                        0x138 /*WAVE_SHR1*/, 0xF, 0xF, true);
    return __builtin_bit_cast(float, r);
}
// lane i+1 -> lane i (row below). Lane 63 gets 0 -> masked by edge select.
__device__ __forceinline__ float dpp_shl1(float x) {
    int r = __builtin_amdgcn_update_dpp(0, __builtin_bit_cast(int, x),
                                        0x130 /*WAVE_SHL1*/, 0xF, 0xF, true);
    return __builtin_bit_cast(float, r);
}

// One full-GS sweep along the register line. Row layout: FWD = L->R (covers
// {R, UR, DR} with UPDATED values), BWD = R->L ({L, UL, DL}). Col layout with
// the same code: FWD = T->B ({D, DR, DL}), BWD = B->T ({U, UR, UL}).
// Every step mins over ALL 8 neighbors (updated where available, else current
// register values), so one clean sweep == Jacobi fixed-point certificate.
// Update algebra is exactly the reference's: nd = min(cur, fl(w + min(nbrs)));
// min(fl(w+a), fl(w+b)) == fl(w+min(a,b)) by rounding monotonicity, so the
// chain split (pre/nd) is exact. Monotone operator + chaotic iteration ->
// unique least fixed point, bit-identical to the reference's 1024 Jacobi sweeps.
template<bool FWD>
__device__ __forceinline__ float sweep32(float (&cur)[32], const float (&w)[32],
                                         const bool tEdge, const bool bEdge) {
    float mx = 0.0f;
    float prev  = INFV;                                   // halo beyond the start
    float shr_c = dpp_shr1(cur[FWD ? 0 : 31]);            // (i-1, start col), old
    float shl_c = dpp_shl1(cur[FWD ? 0 : 31]);            // (i+1, start col), old
#pragma unroll
    for (int s = 0; s < 32; ++s) {
        const int j = FWD ? s : 31 - s;
        const float nxt = FWD ? ((j < 31) ? cur[j + 1] : INFV)
                              : ((j > 0)  ? cur[j - 1] : INFV);   // ahead, old
        const float shr_p = dpp_shr1(prev);               // (i-1, behind) UPDATED
        const float shl_p = dpp_shl1(prev);               // (i+1, behind) UPDATED
        const float shr_n = dpp_shr1(nxt);                // (i-1, ahead) old
        const float shl_n = dpp_shl1(nxt);                // (i+1, ahead) old
        float topm = fminf(fminf(shr_p, shr_c), shr_n);   // row i-1 trio
        float botm = fminf(fminf(shl_p, shl_c), shl_n);   // row i+1 trio
        topm = tEdge ? INFV : topm;                       // grid edge / cross-half mask
        botm = bEdge ? INFV : botm;
        const float off = fminf(fminf(topm, botm), nxt);  // 7 nbrs, off-chain
        const float pre = fminf(cur[j], w[j] + off);
        const float nd  = fminf(pre, w[j] + prev);        // chain: add+min through prev
        mx = fmaxf(mx, cur[j] - nd);                      // >0 iff changed (monotone)
        cur[j] = nd;
        prev = nd;
        shr_c = shr_n;                                    // rolling reuse of old dpp
        shl_c = shl_n;
    }
    return mx;
}

// One wave per block, 2 batches/wave (lanes 0-31 = batch A rows/cols, 32-63 = B).
// Grid state lives in VGPRs; LDS used only for transposes, staging, backtrack.
__global__ __launch_bounds__(64)
void bbastar_kernel(const float* __restrict__ weights,
                    const int* __restrict__ source,
                    const int* __restrict__ target,
                    float* __restrict__ out) {
    __shared__ float g[2][GSZ];    // padded grid: cell (r,c) at (r+1)*GP + c+1; halo = INFV
    __shared__ float wl[2][WSZ];   // weights+EPS staging: cell (r,c) at r*WP + c

    const int lane = threadIdx.x;
    const int line = lane & 31;
    const int sb   = lane >> 5;
    const int gb   = blockIdx.x * 2 + sb;

    // zero both batches' output (harness poisons d_out with 0xAA)
    {
        const float4 z = make_float4(0.f, 0.f, 0.f, 0.f);
        float4* og = (float4*)(out + (size_t)blockIdx.x * 2048);
#pragma unroll
        for (int i = 0; i < 8; ++i) og[lane + (i << 6)] = z;
    }
    // stage weights (+EPS, single f32 add as reference) into LDS, coalesced
    {
        const float4* wg4 = (const float4*)(weights + (size_t)blockIdx.x * 2048);
#pragma unroll
        for (int i = 0; i < 8; ++i) {
            const int idx = lane + (i << 6);          // 0..511 float4s
            const float4 v = wg4[idx];
            const int fi = idx << 2;
            const int bb = fi >> 10, rr = (fi >> 5) & 31, cc = fi & 31;
            float* p = &wl[bb][rr * WP + cc];
            p[0] = v.x + EPSV; p[1] = v.y + EPSV; p[2] = v.z + EPSV; p[3] = v.w + EPSV;
        }
    }
    // INF-fill padded grids (halo ring must be INFV; interior overwritten later)
    {
        const float4 inf4 = make_float4(INFV, INFV, INFV, INFV);
        float4* df = (float4*)&g[0][0];               // 2*1192/4 = 596 float4s
#pragma unroll
        for (int i = 0; i < 10; ++i) {
            const int idx = lane + (i << 6);
            if (idx < 596) df[idx] = inf4;
        }
    }
    __syncthreads();

    const int sr = source[2 * gb], sc = source[2 * gb + 1];
    const float wsrc = wl[sb][sr * WP + sc];

    // register state: weights in both orientations + current dist line
    float wrow[32], wcol[32], cur[32];
#pragma unroll
    for (int j = 0; j < 32; ++j) {
        wrow[j] = wl[sb][line * WP + j];      // (row=line, col=j)
        wcol[j] = wl[sb][j * WP + line];      // (row=j, col=line)
        cur[j]  = ((line == sr) && (j == sc)) ? wsrc : INFV;   // row layout
    }

    const bool tE = (line == 0), bE = (line == 31);
    float* gg = g[sb];
    bool colmode = false;

    // 4-ordering fast sweeping: R, L (row layout), transpose, D, U (col
    // layout), transpose back. Early exit on any clean sweep (certificate).
    for (int it = 0; it < 512; ++it) {
        const int ph = it & 3;
        float mx;
        if (ph == 0)      mx = sweep32<true >(cur, wrow, tE, bE);
        else if (ph == 1) mx = sweep32<false>(cur, wrow, tE, bE);
        else if (ph == 2) mx = sweep32<true >(cur, wcol, tE, bE);
        else              mx = sweep32<false>(cur, wcol, tE, bE);
        if (__ballot(mx > 0.0f) == 0ULL) break;     // both batches at fixed point
        if (ph == 1) {            // row -> col transpose (b32, odd pitch: conflict-free)
#pragma unroll
            for (int j = 0; j < 32; ++j) gg[(line + 1) * GP + 1 + j] = cur[j];
            __asm__ __volatile__("" ::: "memory");
#pragma unroll
            for (int j = 0; j < 32; ++j) cur[j] = gg[(j + 1) * GP + 1 + line];
            colmode = true;
        } else if (ph == 3) {     // col -> row transpose
#pragma unroll
            for (int j = 0; j < 32; ++j) gg[(j + 1) * GP + 1 + line] = cur[j];
            __asm__ __volatile__("" ::: "memory");
#pragma unroll
            for (int j = 0; j < 32; ++j) cur[j] = gg[(line + 1) * GP + 1 + j];
            colmode = false;
        }
    }

    // write final dist into the padded LDS grid for the backtrack
    if (!colmode) {
#pragma unroll
        for (int j = 0; j < 32; ++j) gg[(line + 1) * GP + 1 + j] = cur[j];
    } else {
#pragma unroll
        for (int j = 0; j < 32; ++j) gg[(j + 1) * GP + 1 + line] = cur[j];
    }
    __syncthreads();

    // Greedy backtrack, lanes 0 (batch A) and 32 (batch B) concurrently.
    // Halo ring = INFV matches reference's where(valid, ., INF); strict '<'
    // scan in OFFS order replicates jnp.argmin first-min tie-breaking.
    if (line == 0) {
        const int drr[8] = {-1, -1, -1,  0, 0,  1, 1, 1};
        const int dcc[8] = {-1,  0,  1, -1, 1, -1, 0, 1};
        int pr = target[2 * gb], pc = target[2 * gb + 1];
        float* ob = out + (size_t)gb * 1024;
        for (int step = 0; step < 1024; ++step) {
            ob[pr * 32 + pc] = 1.0f;
            if (pr == sr && pc == sc) break;
            float best = INFV; int bj = 0;
#pragma unroll
            for (int j = 0; j < 8; ++j) {
                const float v = gg[(pr + drr[j] + 1) * GP + (pc + dcc[j] + 1)];
                if (v < best) { best = v; bj = j; }
            }
            pr += drr[bj];
            pc += dcc[bj];
        }
    }
}

extern "C" void kernel_launch(void* const* d_in, const int* in_sizes, int n_in,
                              void* d_out, int out_size, void* d_ws, size_t ws_size,
                              hipStream_t stream) {
    const float* weights = (const float*)d_in[0];
    const int*   source  = (const int*)d_in[1];
    const int*   target  = (const int*)d_in[2];
    float*       out     = (float*)d_out;
    const int B = in_sizes[0] / 1024;
    bbastar_kernel<<<B / 2, 64, 0, stream>>>(weights, source, target, out);
}